// Round 1
// baseline (344.636 us; speedup 1.0000x reference)
//
#include <hip/hip_runtime.h>

// Problem constants (fixed shapes from setup_inputs)
#define BATCH 2
#define HH 64
#define WW 64
#define CC 128
#define OHH 32
#define OWW 32
#define NPOOL (OHH * OWW * CC)              // 131072
#define NOUT 32
#define NIN (HH * WW * CC)                  // 524288
#define WZERO ((size_t)BATCH * NIN * NOUT)  // 33554432 floats per w_zero output

// Flat float offsets into d_out, concatenated in return order:
// w_zero(33554432) | b_out_u_(64) | w_zero(33554432) | b_out_l_(64)
#define OFF_BU (WZERO)
#define OFF_BL (2 * WZERO + (size_t)BATCH * NOUT)

#define CHUNKS 128                  // reduce blocks per batch element
#define PPC (NPOOL / CHUNKS)        // 1024 pooled positions per block
#define RBLOCKS (BATCH * CHUNKS)    // 256 reduce blocks

#define ZBLOCKS 2048                          // dedicated zero-fill blocks
#define ZQUADS ((2 * WZERO) / 4)              // 16,777,216 float4s to zero
#define ZPB (ZQUADS / ZBLOCKS)                // 8192 float4s per zero block
#define R1Q (WZERO / 4)                       // float4s in first w_zero region
#define GAPQ (((size_t)BATCH * NOUT) / 4)     // 16 float4s of bias between regions

typedef float f4v __attribute__((ext_vector_type(4)));

// One kernel, two block roles:
//  - blocks [0, RBLOCKS): inline maxpool (u_c,l_c -> LDS) + weight-fold
//    partial reduction for one (batch, chunk); partials -> workspace.
//  - blocks [RBLOCKS, RBLOCKS+ZBLOCKS): nontemporal float4 zero-fill of the
//    two w_zero output regions (bias slots excluded).
// The 268 MB write stream and 72 MB read stream overlap across CUs.
__global__ void __launch_bounds__(256) fused_kernel(
        const float4* __restrict__ u_c,
        const float4* __restrict__ l_c,
        const float4* __restrict__ wu,
        const float4* __restrict__ wl,
        float4* __restrict__ partial,     // RBLOCKS * 16 float4 (64 KB)
        float* __restrict__ out) {
    const int blk = blockIdx.x;
    const int t = threadIdx.x;

    if (blk >= RBLOCKS) {
        // ---- zero-fill path ----
        const size_t z0 = (size_t)(blk - RBLOCKS) * ZPB;
        f4v zero = {0.f, 0.f, 0.f, 0.f};
        f4v* o4 = (f4v*)out;
        #pragma unroll
        for (int i = 0; i < ZPB / 256; ++i) {
            size_t q = z0 + (size_t)i * 256 + t;
            size_t addr = (q < R1Q) ? q : q + GAPQ;   // hop over bias_u slot
            __builtin_nontemporal_store(zero, o4 + addr);
        }
        return;
    }

    // ---- reduce path ----
    const int b = blk / CHUNKS;
    const int chunk = blk % CHUNKS;

    __shared__ float4 pu4[256];   // pooled u, 1024 floats (8 spatial x 128 ch)
    __shared__ float4 pl4[256];   // pooled l

    {
        // Inline 2x2 maxpool for this chunk's 8 spatial positions x 128 ch.
        // t = sp*32 + c4  (sp: spatial-in-chunk, c4: channel quad)
        const int sp = t >> 5;
        const int c4 = t & 31;
        const int s = chunk * 8 + sp;       // flat pooled spatial index
        const int oh = s >> 5;
        const int ow = s & 31;
        const int base = ((b * HH + 2 * oh) * WW + 2 * ow) * (CC / 4) + c4;
        const int cs = CC / 4;              // +1 in w (float4 units)
        const int rs = WW * (CC / 4);       // +1 in h
        {
            float4 a0 = u_c[base];
            float4 a1 = u_c[base + cs];
            float4 a2 = u_c[base + rs];
            float4 a3 = u_c[base + rs + cs];
            float4 m;
            m.x = fmaxf(fmaxf(a0.x, a1.x), fmaxf(a2.x, a3.x));
            m.y = fmaxf(fmaxf(a0.y, a1.y), fmaxf(a2.y, a3.y));
            m.z = fmaxf(fmaxf(a0.z, a1.z), fmaxf(a2.z, a3.z));
            m.w = fmaxf(fmaxf(a0.w, a1.w), fmaxf(a2.w, a3.w));
            pu4[t] = m;
        }
        {
            float4 a0 = l_c[base];
            float4 a1 = l_c[base + cs];
            float4 a2 = l_c[base + rs];
            float4 a3 = l_c[base + rs + cs];
            float4 m;
            m.x = fmaxf(fmaxf(a0.x, a1.x), fmaxf(a2.x, a3.x));
            m.y = fmaxf(fmaxf(a0.y, a1.y), fmaxf(a2.y, a3.y));
            m.z = fmaxf(fmaxf(a0.z, a1.z), fmaxf(a2.z, a3.z));
            m.w = fmaxf(fmaxf(a0.w, a1.w), fmaxf(a2.w, a3.w));
            pl4[t] = m;
        }
    }
    __syncthreads();

    const float* puf = (const float*)pu4;
    const float* plf = (const float*)pl4;

    // Thread layout: og = t&7 (float4 of the 32 outputs), plane = t>>3.
    // Consecutive t -> consecutive float4s of w -> 1 KB/wave coalesced loads.
    const int og = t & 7;
    const int pln = t >> 3;

    float4 au = make_float4(0.f, 0.f, 0.f, 0.f);
    float4 al = make_float4(0.f, 0.f, 0.f, 0.f);

    const size_t wbase =
        ((size_t)b * NPOOL + (size_t)chunk * PPC) * (NOUT / 4) + og;

    #pragma unroll 4
    for (int k = 0; k < PPC / 32; ++k) {
        const int lp = pln + 32 * k;                 // local pooled index
        const float vbu = puf[lp];
        const float vbl = plf[lp];
        const float4 u4 = wu[wbase + (size_t)lp * (NOUT / 4)];
        const float4 l4 = wl[wbase + (size_t)lp * (NOUT / 4)];
        au.x += fmaxf(u4.x, 0.f) * vbu + fminf(u4.x, 0.f) * vbl;
        au.y += fmaxf(u4.y, 0.f) * vbu + fminf(u4.y, 0.f) * vbl;
        au.z += fmaxf(u4.z, 0.f) * vbu + fminf(u4.z, 0.f) * vbl;
        au.w += fmaxf(u4.w, 0.f) * vbu + fminf(u4.w, 0.f) * vbl;
        al.x += fmaxf(l4.x, 0.f) * vbl + fminf(l4.x, 0.f) * vbu;
        al.y += fmaxf(l4.y, 0.f) * vbl + fminf(l4.y, 0.f) * vbu;
        al.z += fmaxf(l4.z, 0.f) * vbl + fminf(l4.z, 0.f) * vbu;
        al.w += fmaxf(l4.w, 0.f) * vbl + fminf(l4.w, 0.f) * vbu;
    }

    // Reuse the pool LDS for the cross-plane tree reduce.
    __syncthreads();
    pu4[t] = au;
    pl4[t] = al;
    __syncthreads();
    for (int s = 128; s >= 8; s >>= 1) {
        if (t < s) {
            float4 xu = pu4[t + s];
            pu4[t].x += xu.x; pu4[t].y += xu.y;
            pu4[t].z += xu.z; pu4[t].w += xu.w;
            float4 xl = pl4[t + s];
            pl4[t].x += xl.x; pl4[t].y += xl.y;
            pl4[t].z += xl.z; pl4[t].w += xl.w;
        }
        __syncthreads();
    }

    // Per-chunk partials: [blk][u:8 float4 | l:8 float4], no atomics.
    if (t < 8) {
        partial[(size_t)blk * 16 + t] = pu4[t];
        partial[(size_t)blk * 16 + 8 + t] = pl4[t];
    }
}

// Folds the 256 per-chunk partials with b_out_u/b_out_l and writes the 128
// bias floats directly (full overwrite: no pre-zero, no atomics needed).
__global__ void finish_kernel(const float* __restrict__ partial,
                              const float* __restrict__ b_out_u,
                              const float* __restrict__ b_out_l,
                              float* __restrict__ out) {
    const int t = threadIdx.x;       // 128 threads
    const int b = t >> 6;            // batch
    const int uo = (t >> 5) & 1;     // 0 = upper, 1 = lower
    const int o = t & 31;            // output column
    float s = 0.f;
    for (int chunk = 0; chunk < CHUNKS; ++chunk) {
        s += partial[((size_t)(b * CHUNKS + chunk)) * 64 + uo * 32 + o];
    }
    if (uo == 0) {
        out[OFF_BU + (size_t)b * NOUT + o] = s + b_out_u[b * NOUT + o];
    } else {
        out[OFF_BL + (size_t)b * NOUT + o] = s + b_out_l[b * NOUT + o];
    }
}

extern "C" void kernel_launch(void* const* d_in, const int* in_sizes, int n_in,
                              void* d_out, int out_size, void* d_ws, size_t ws_size,
                              hipStream_t stream) {
    // setup_inputs order: y, x_0, u_c, l_c, w_out_u, b_out_u, w_out_l, b_out_l
    const float* u_c     = (const float*)d_in[2];
    const float* l_c     = (const float*)d_in[3];
    const float* w_out_u = (const float*)d_in[4];
    const float* b_out_u = (const float*)d_in[5];
    const float* w_out_l = (const float*)d_in[6];
    const float* b_out_l = (const float*)d_in[7];
    float* out = (float*)d_out;

    float4* ws_partial = (float4*)d_ws;   // RBLOCKS * 16 float4 = 64 KB

    // 1) Fused: zero-fill w_zero regions + inline-pool + partial weight-fold.
    fused_kernel<<<RBLOCKS + ZBLOCKS, 256, 0, stream>>>(
        (const float4*)u_c, (const float4*)l_c,
        (const float4*)w_out_u, (const float4*)w_out_l,
        ws_partial, out);

    // 2) Tiny finish: fold partials + biases, write the 128 bias floats.
    finish_kernel<<<1, 128, 0, stream>>>(
        (const float*)ws_partial, b_out_u, b_out_l, out);
}

// Round 2
// 338.315 us; speedup vs baseline: 1.0187x; 1.0187x over previous
//
#include <hip/hip_runtime.h>

// Problem constants (fixed shapes from setup_inputs)
#define BATCH 2
#define HH 64
#define WW 64
#define CC 128
#define OHH 32
#define OWW 32
#define NPOOL (OHH * OWW * CC)              // 131072
#define NOUT 32
#define NIN (HH * WW * CC)                  // 524288
#define WZERO ((size_t)BATCH * NIN * NOUT)  // 33554432 floats per w_zero output

// Flat float offsets into d_out, concatenated in return order:
// w_zero(33554432) | b_out_u_(64) | w_zero(33554432) | b_out_l_(64)
#define OFF_BU (WZERO)
#define OFF_BL (2 * WZERO + (size_t)BATCH * NOUT)

#define CHUNKS 128                  // reduce blocks per batch element
#define PPC (NPOOL / CHUNKS)        // 1024 pooled positions per block
#define RBLOCKS (BATCH * CHUNKS)    // 256 reduce blocks

#define ZBLOCKS 2048                          // dedicated zero-fill blocks
#define ZQUADS ((2 * WZERO) / 4)              // 16,777,216 float4s to zero
#define ZPB (ZQUADS / ZBLOCKS)                // 8192 float4s per zero block
#define R1Q (WZERO / 4)                       // float4s in first w_zero region
#define GAPQ (((size_t)BATCH * NOUT) / 4)     // 16 float4s of bias between regions

// One kernel, two block roles:
//  - blocks [0, RBLOCKS): inline maxpool (u_c,l_c -> LDS) + weight-fold
//    partial reduction for one (batch, chunk); partials -> workspace.
//  - blocks [RBLOCKS, RBLOCKS+ZBLOCKS): PLAIN float4 zero-fill of the two
//    w_zero output regions (bias slots excluded). NT stores removed: the
//    harness's own fillBuffer proves plain stores sustain 6.2 TB/s here,
//    while the NT path measured ~3x slower (suspected partial-line writes).
// The 268 MB write stream and 72 MB read stream overlap across CUs.
__global__ void __launch_bounds__(256) fused_kernel(
        const float4* __restrict__ u_c,
        const float4* __restrict__ l_c,
        const float4* __restrict__ wu,
        const float4* __restrict__ wl,
        float4* __restrict__ partial,     // RBLOCKS * 16 float4 (64 KB)
        float* __restrict__ out) {
    const int blk = blockIdx.x;
    const int t = threadIdx.x;

    if (blk >= RBLOCKS) {
        // ---- zero-fill path: plain coalesced float4 stores ----
        const size_t z0 = (size_t)(blk - RBLOCKS) * ZPB;
        const float4 zero = make_float4(0.f, 0.f, 0.f, 0.f);
        float4* o4 = (float4*)out;
        #pragma unroll
        for (int i = 0; i < ZPB / 256; ++i) {
            size_t q = z0 + (size_t)i * 256 + t;
            size_t addr = (q < R1Q) ? q : q + GAPQ;   // hop over bias_u slot
            o4[addr] = zero;
        }
        return;
    }

    // ---- reduce path ----
    const int b = blk / CHUNKS;
    const int chunk = blk % CHUNKS;

    __shared__ float4 pu4[256];   // pooled u, 1024 floats (8 spatial x 128 ch)
    __shared__ float4 pl4[256];   // pooled l

    {
        // Inline 2x2 maxpool for this chunk's 8 spatial positions x 128 ch.
        // t = sp*32 + c4  (sp: spatial-in-chunk, c4: channel quad)
        const int sp = t >> 5;
        const int c4 = t & 31;
        const int s = chunk * 8 + sp;       // flat pooled spatial index
        const int oh = s >> 5;
        const int ow = s & 31;
        const int base = ((b * HH + 2 * oh) * WW + 2 * ow) * (CC / 4) + c4;
        const int cs = CC / 4;              // +1 in w (float4 units)
        const int rs = WW * (CC / 4);       // +1 in h
        {
            float4 a0 = u_c[base];
            float4 a1 = u_c[base + cs];
            float4 a2 = u_c[base + rs];
            float4 a3 = u_c[base + rs + cs];
            float4 m;
            m.x = fmaxf(fmaxf(a0.x, a1.x), fmaxf(a2.x, a3.x));
            m.y = fmaxf(fmaxf(a0.y, a1.y), fmaxf(a2.y, a3.y));
            m.z = fmaxf(fmaxf(a0.z, a1.z), fmaxf(a2.z, a3.z));
            m.w = fmaxf(fmaxf(a0.w, a1.w), fmaxf(a2.w, a3.w));
            pu4[t] = m;
        }
        {
            float4 a0 = l_c[base];
            float4 a1 = l_c[base + cs];
            float4 a2 = l_c[base + rs];
            float4 a3 = l_c[base + rs + cs];
            float4 m;
            m.x = fmaxf(fmaxf(a0.x, a1.x), fmaxf(a2.x, a3.x));
            m.y = fmaxf(fmaxf(a0.y, a1.y), fmaxf(a2.y, a3.y));
            m.z = fmaxf(fmaxf(a0.z, a1.z), fmaxf(a2.z, a3.z));
            m.w = fmaxf(fmaxf(a0.w, a1.w), fmaxf(a2.w, a3.w));
            pl4[t] = m;
        }
    }
    __syncthreads();

    const float* puf = (const float*)pu4;
    const float* plf = (const float*)pl4;

    // Thread layout: og = t&7 (float4 of the 32 outputs), plane = t>>3.
    // Consecutive t -> consecutive float4s of w -> 1 KB/wave coalesced loads.
    const int og = t & 7;
    const int pln = t >> 3;

    float4 au = make_float4(0.f, 0.f, 0.f, 0.f);
    float4 al = make_float4(0.f, 0.f, 0.f, 0.f);

    const size_t wbase =
        ((size_t)b * NPOOL + (size_t)chunk * PPC) * (NOUT / 4) + og;

    // Deeper unroll: reduce blocks are ~1/9 of resident waves, so each
    // needs more loads in flight to claim its share of HBM read BW.
    #pragma unroll 8
    for (int k = 0; k < PPC / 32; ++k) {
        const int lp = pln + 32 * k;                 // local pooled index
        const float vbu = puf[lp];
        const float vbl = plf[lp];
        const float4 u4 = wu[wbase + (size_t)lp * (NOUT / 4)];
        const float4 l4 = wl[wbase + (size_t)lp * (NOUT / 4)];
        au.x += fmaxf(u4.x, 0.f) * vbu + fminf(u4.x, 0.f) * vbl;
        au.y += fmaxf(u4.y, 0.f) * vbu + fminf(u4.y, 0.f) * vbl;
        au.z += fmaxf(u4.z, 0.f) * vbu + fminf(u4.z, 0.f) * vbl;
        au.w += fmaxf(u4.w, 0.f) * vbu + fminf(u4.w, 0.f) * vbl;
        al.x += fmaxf(l4.x, 0.f) * vbl + fminf(l4.x, 0.f) * vbu;
        al.y += fmaxf(l4.y, 0.f) * vbl + fminf(l4.y, 0.f) * vbu;
        al.z += fmaxf(l4.z, 0.f) * vbl + fminf(l4.z, 0.f) * vbu;
        al.w += fmaxf(l4.w, 0.f) * vbl + fminf(l4.w, 0.f) * vbu;
    }

    // Reuse the pool LDS for the cross-plane tree reduce.
    __syncthreads();
    pu4[t] = au;
    pl4[t] = al;
    __syncthreads();
    for (int s = 128; s >= 8; s >>= 1) {
        if (t < s) {
            float4 xu = pu4[t + s];
            pu4[t].x += xu.x; pu4[t].y += xu.y;
            pu4[t].z += xu.z; pu4[t].w += xu.w;
            float4 xl = pl4[t + s];
            pl4[t].x += xl.x; pl4[t].y += xl.y;
            pl4[t].z += xl.z; pl4[t].w += xl.w;
        }
        __syncthreads();
    }

    // Per-chunk partials: [blk][u:8 float4 | l:8 float4], no atomics.
    if (t < 8) {
        partial[(size_t)blk * 16 + t] = pu4[t];
        partial[(size_t)blk * 16 + 8 + t] = pl4[t];
    }
}

// Folds the 256 per-chunk partials with b_out_u/b_out_l and writes the 128
// bias floats directly (full overwrite: no pre-zero, no atomics needed).
__global__ void finish_kernel(const float* __restrict__ partial,
                              const float* __restrict__ b_out_u,
                              const float* __restrict__ b_out_l,
                              float* __restrict__ out) {
    const int t = threadIdx.x;       // 128 threads
    const int b = t >> 6;            // batch
    const int uo = (t >> 5) & 1;     // 0 = upper, 1 = lower
    const int o = t & 31;            // output column
    float s = 0.f;
    for (int chunk = 0; chunk < CHUNKS; ++chunk) {
        s += partial[((size_t)(b * CHUNKS + chunk)) * 64 + uo * 32 + o];
    }
    if (uo == 0) {
        out[OFF_BU + (size_t)b * NOUT + o] = s + b_out_u[b * NOUT + o];
    } else {
        out[OFF_BL + (size_t)b * NOUT + o] = s + b_out_l[b * NOUT + o];
    }
}

extern "C" void kernel_launch(void* const* d_in, const int* in_sizes, int n_in,
                              void* d_out, int out_size, void* d_ws, size_t ws_size,
                              hipStream_t stream) {
    // setup_inputs order: y, x_0, u_c, l_c, w_out_u, b_out_u, w_out_l, b_out_l
    const float* u_c     = (const float*)d_in[2];
    const float* l_c     = (const float*)d_in[3];
    const float* w_out_u = (const float*)d_in[4];
    const float* b_out_u = (const float*)d_in[5];
    const float* w_out_l = (const float*)d_in[6];
    const float* b_out_l = (const float*)d_in[7];
    float* out = (float*)d_out;

    float4* ws_partial = (float4*)d_ws;   // RBLOCKS * 16 float4 = 64 KB

    // 1) Fused: zero-fill w_zero regions + inline-pool + partial weight-fold.
    fused_kernel<<<RBLOCKS + ZBLOCKS, 256, 0, stream>>>(
        (const float4*)u_c, (const float4*)l_c,
        (const float4*)w_out_u, (const float4*)w_out_l,
        ws_partial, out);

    // 2) Tiny finish: fold partials + biases, write the 128 bias floats.
    finish_kernel<<<1, 128, 0, stream>>>(
        (const float*)ws_partial, b_out_u, b_out_l, out);
}